// Round 6
// baseline (568.638 us; speedup 1.0000x reference)
//
#include <hip/hip_runtime.h>
#include <hip/hip_bf16.h>

#define NT 557056
typedef __hip_bfloat16 bf16;
typedef __attribute__((ext_vector_type(8))) short short8;
typedef __attribute__((ext_vector_type(4))) short short4v;
typedef __attribute__((ext_vector_type(4))) float f32x4;

// Tiled intermediate layout: [tile of 32 positions][64 ch][32 shorts],
// within-tile order p' = g*8 + th*4 + q  <->  tile-local pos p = th*16 + 4g + q.
// One MFMA C-fragment (both th halves) = one short8 at (ch)*32 + g*8: stores
// and loads are 1KB-contiguous per instruction (full cache lines).

__device__ __forceinline__ short f2bs(float f){ bf16 h = __float2bfloat16(f); return *(short*)&h; }
__device__ __forceinline__ float s2f(short s){ bf16 h = *(bf16*)&s; return __bfloat162float(h); }

__device__ __forceinline__ short8 cvt8(float4 a, float4 b){
  short8 r;
  r[0]=f2bs(a.x); r[1]=f2bs(a.y); r[2]=f2bs(a.z); r[3]=f2bs(a.w);
  r[4]=f2bs(b.x); r[5]=f2bs(b.y); r[6]=f2bs(b.z); r[7]=f2bs(b.w);
  return r;
}
// 8 consecutive f32 -> bf16x8 MFMA fragment.
// A-role: lane holds A[row=l&15][k=(l>>4)*8+j]; B-role: B[k=(l>>4)*8+j][col=l&15].
__device__ __forceinline__ short8 ldfrag(const float* __restrict__ p){
  return cvt8(*(const float4*)p, *(const float4*)(p + 4));
}
__device__ __forceinline__ short8 ldfrag_s(const float* __restrict__ p, float s){
  float4 a = *(const float4*)p, b = *(const float4*)(p + 4);
  a.x*=s; a.y*=s; a.z*=s; a.w*=s; b.x*=s; b.y*=s; b.z*=s; b.w*=s;
  return cvt8(a, b);
}
#define MFMA(a,b,c) __builtin_amdgcn_mfma_f32_16x16x32_bf16(a, b, c, 0, 0, 0)

#define LS 72   // LDS row stride in shorts (144B rows, 16B-aligned)

// ---------------------------------------------------------------------------
// K1: m1 = MLP(x; w_m1), m2 = MLP(x; w_m2). 4352 waves x 4 tiles x 32 pos.
// Weights register-resident; wave-private LDS transpose; no barriers.
// Stores: tiled layout, 1KB-contiguous short8 per instruction.
// ---------------------------------------------------------------------------
__global__ __launch_bounds__(256, 2) void k1_mlp(
    const float* __restrict__ x,
    const float* __restrict__ w_m1, const float* __restrict__ b_m1,
    const float* __restrict__ w_m2, const float* __restrict__ b_m2,
    bf16* __restrict__ m1t, bf16* __restrict__ m2t)
{
  __shared__ short yL[4][32][LS];   // [wave][pos][ch+pad], reused across m
  const int tid = threadIdx.x;
  const int wv = tid >> 6, lane = tid & 63, r = lane & 15, g = lane >> 4;
  const int wid = blockIdx.x * 4 + wv;   // 0..4351

  // ---- hoist weights (once per wave) ----
  short8 wf[4][4][2];   // [m1L0,m1L1,m2L0,m2L1][cb][s]
  #pragma unroll
  for (int cb = 0; cb < 4; ++cb)
    #pragma unroll
    for (int s = 0; s < 2; ++s) {
      const int o = (cb*16 + r)*64 + s*32 + g*8;
      wf[0][cb][s] = ldfrag(w_m1 + o);
      wf[1][cb][s] = ldfrag(w_m1 + 4096 + o);
      wf[2][cb][s] = ldfrag(w_m2 + o);
      wf[3][cb][s] = ldfrag(w_m2 + 4096 + o);
    }
  f32x4 b0v[2][4];  // L0 bias (transposed C: rows=ch=4g+q)
  float b1v[2][4];  // L1 bias (normal C: col=ch=r)
  #pragma unroll
  for (int m = 0; m < 2; ++m) {
    const float* bb = m ? b_m2 : b_m1;
    #pragma unroll
    for (int cb = 0; cb < 4; ++cb) {
      b0v[m][cb] = *(const f32x4*)(bb + cb*16 + 4*g);
      b1v[m][cb] = bb[64 + cb*16 + r];
    }
  }

  size_t pb = (size_t)wid * 128;

  float4 xr[8];
  #pragma unroll
  for (int h = 0; h < 2; ++h) {
    const float* xp = x + (pb + h*16 + r)*64 + g*8;
    xr[4*h+0] = *(const float4*)(xp);
    xr[4*h+1] = *(const float4*)(xp + 4);
    xr[4*h+2] = *(const float4*)(xp + 32);
    xr[4*h+3] = *(const float4*)(xp + 36);
  }

  for (int t = 0; t < 4; ++t, pb += 32) {
    short8 xf[2][2];
    xf[0][0] = cvt8(xr[0], xr[1]);  xf[0][1] = cvt8(xr[2], xr[3]);
    xf[1][0] = cvt8(xr[4], xr[5]);  xf[1][1] = cvt8(xr[6], xr[7]);
    if (t < 3) {   // prefetch next tile under this tile's compute
      #pragma unroll
      for (int h = 0; h < 2; ++h) {
        const float* xp = x + (pb + 32 + h*16 + r)*64 + g*8;
        xr[4*h+0] = *(const float4*)(xp);
        xr[4*h+1] = *(const float4*)(xp + 4);
        xr[4*h+2] = *(const float4*)(xp + 32);
        xr[4*h+3] = *(const float4*)(xp + 36);
      }
    }
    const size_t tbase = (pb >> 5) * 2048;   // tile base (shorts)
    #pragma unroll
    for (int m = 0; m < 2; ++m) {
      // L0 transposed: C[row=ch(4g+q)][col=pos(r)]
      f32x4 acc[4][2];
      #pragma unroll
      for (int cb = 0; cb < 4; ++cb) { acc[cb][0] = b0v[m][cb]; acc[cb][1] = b0v[m][cb]; }
      #pragma unroll
      for (int cb = 0; cb < 4; ++cb)
        #pragma unroll
        for (int s = 0; s < 2; ++s) {
          acc[cb][0] = MFMA(wf[2*m][cb][s], xf[0][s], acc[cb][0]);
          acc[cb][1] = MFMA(wf[2*m][cb][s], xf[1][s], acc[cb][1]);
        }
      #pragma unroll
      for (int cb = 0; cb < 4; ++cb)
        #pragma unroll
        for (int th = 0; th < 2; ++th) {
          short4v v;
          #pragma unroll
          for (int q = 0; q < 4; ++q) v[q] = f2bs(fmaxf(acc[cb][th][q], 0.f));
          *(short4v*)&yL[wv][th*16 + r][cb*16 + 4*g] = v;   // [pos][ch-run]
        }
      short8 af[2][2];
      #pragma unroll
      for (int th = 0; th < 2; ++th)
        #pragma unroll
        for (int s = 0; s < 2; ++s)
          af[th][s] = *(const short8*)&yL[wv][th*16 + r][s*32 + g*8];
      // L1 normal: C[row=pos(4g+q)][col=ch(r)]
      f32x4 acc2[4][2];
      #pragma unroll
      for (int cb = 0; cb < 4; ++cb) {
        const float bv = b1v[m][cb];
        acc2[cb][0] = (f32x4){bv,bv,bv,bv};
        acc2[cb][1] = (f32x4){bv,bv,bv,bv};
      }
      #pragma unroll
      for (int cb = 0; cb < 4; ++cb)
        #pragma unroll
        for (int s = 0; s < 2; ++s) {
          acc2[cb][0] = MFMA(af[0][s], wf[2*m+1][cb][s], acc2[cb][0]);
          acc2[cb][1] = MFMA(af[1][s], wf[2*m+1][cb][s], acc2[cb][1]);
        }
      bf16* op = m ? m2t : m1t;
      #pragma unroll
      for (int cb = 0; cb < 4; ++cb) {
        short8 v;
        #pragma unroll
        for (int th = 0; th < 2; ++th)
          #pragma unroll
          for (int q = 0; q < 4; ++q) v[th*4+q] = f2bs(fmaxf(acc2[cb][th][q], 0.f));
        // tiled layout: ch=cb*16+r, p'=g*8..g*8+7 -> 1KB-contiguous per inst
        *(short8*)(op + tbase + (cb*16 + r)*32 + g*8) = v;
      }
    }
  }
}

// ---------------------------------------------------------------------------
// K2: per (block, channel) spatial matmul H = M1 @ M2 (n x n).
// Loads/stores in the tiled layout (full-line footprints); epilogue goes
// acc -> LDS -> permuted coalesced short8 stores. ht aliases m1t (the block
// fully stages its plane in LDS before any store).
// ---------------------------------------------------------------------------
template<int N>
__global__ __launch_bounds__(256) void k2_spatial(
    const bf16* __restrict__ m1t, const bf16* __restrict__ m2t,
    bf16* __restrict__ ht, int off)
{
  constexpr int T = N / 16;
  constexpr int SA = N + 4;
  __shared__ __align__(16) float AT[N*SA];  // AT[k][j] = A[j][k]; reused as Cf
  __shared__ __align__(16) float Bs[N*SA];  // Bs[j][k] = B[j][k]
  const int b = blockIdx.x >> 6;
  const int c = blockIdx.x & 63;
  const size_t base_tile = ((size_t)off + (size_t)b * N * N) >> 5;
  const int tid = threadIdx.x;

  for (int idx8 = tid*8; idx8 < N*N; idx8 += 2048) {
    const size_t gaddr = (base_tile + (idx8 >> 5)) * 2048 + c*32 + (idx8 & 31);
    short8 a8 = *(const short8*)(m1t + gaddr);
    short8 b8 = *(const short8*)(m2t + gaddr);
    const int gsub = (idx8 & 31) >> 3;
    const int i0 = idx8 & ~31;          // tile-local base in pos space
    #pragma unroll
    for (int th = 0; th < 2; ++th) {
      const int i = i0 + th*16 + 4*gsub;   // 4 consecutive positions (N%4==0)
      const int j = i / N, k0 = i - j*N;
      f32x4 bq;
      #pragma unroll
      for (int q = 0; q < 4; ++q) bq[q] = s2f(b8[th*4+q]);
      *(f32x4*)&Bs[j*SA + k0] = bq;
      #pragma unroll
      for (int q = 0; q < 4; ++q) AT[(k0+q)*SA + j] = s2f(a8[th*4+q]);
    }
  }
  __syncthreads();

  const int ti = tid >> 4, tk = tid & 15;
  float acc[T][T];
  #pragma unroll
  for (int ii = 0; ii < T; ++ii)
    #pragma unroll
    for (int kk = 0; kk < T; ++kk) acc[ii][kk] = 0.f;

  for (int j = 0; j < N; ++j) {
    const float* ar = &AT[j*SA + ti*T];
    const float* br = &Bs[j*SA + tk*T];
    float av[T], bv[T];
    if constexpr (T == 2) {
      float2 a2 = *(const float2*)ar; av[0]=a2.x; av[1]=a2.y;
      float2 b2 = *(const float2*)br; bv[0]=b2.x; bv[1]=b2.y;
    } else if constexpr (T == 3) {
      av[0]=ar[0]; av[1]=ar[1]; av[2]=ar[2];
      bv[0]=br[0]; bv[1]=br[1]; bv[2]=br[2];
    } else if constexpr (T == 4) {
      float4 a4 = *(const float4*)ar; av[0]=a4.x; av[1]=a4.y; av[2]=a4.z; av[3]=a4.w;
      float4 b4 = *(const float4*)br; bv[0]=b4.x; bv[1]=b4.y; bv[2]=b4.z; bv[3]=b4.w;
    } else {  // T == 6
      #pragma unroll
      for (int p = 0; p < 3; ++p) {
        float2 a2 = *(const float2*)(ar + 2*p); av[2*p]=a2.x; av[2*p+1]=a2.y;
        float2 b2 = *(const float2*)(br + 2*p); bv[2*p]=b2.x; bv[2*p+1]=b2.y;
      }
    }
    #pragma unroll
    for (int ii = 0; ii < T; ++ii)
      #pragma unroll
      for (int kk = 0; kk < T; ++kk)
        acc[ii][kk] = fmaf(av[ii], bv[kk], acc[ii][kk]);
  }

  __syncthreads();                 // all reads of AT/Bs done
  float* Cf = AT;                  // reuse as flat C plane (n^2 <= N*SA)
  #pragma unroll
  for (int ii = 0; ii < T; ++ii)
    #pragma unroll
    for (int kk = 0; kk < T; ++kk)
      Cf[(ti*T + ii)*N + tk*T + kk] = acc[ii][kk];
  __syncthreads();

  for (int idx8 = tid*8; idx8 < N*N; idx8 += 2048) {
    const int i0 = idx8 & ~31, gsub = (idx8 & 31) >> 3;
    f32x4 lo = *(const f32x4*)&Cf[i0 + 4*gsub];        // th=0 quad
    f32x4 hi = *(const f32x4*)&Cf[i0 + 16 + 4*gsub];   // th=1 quad
    short8 v;
    #pragma unroll
    for (int q = 0; q < 4; ++q) { v[q] = f2bs(lo[q]); v[4+q] = f2bs(hi[q]); }
    const size_t gaddr = (base_tile + (idx8 >> 5)) * 2048 + c*32 + (idx8 & 31);
    *(short8*)(ht + gaddr) = v;
  }
}

// ---------------------------------------------------------------------------
// K3: hs2 = h + x@Wskip^T + b; u1 = relu(bn1(hs2@Wu1^T+bu1));
// u2 = relu(bn2(u1@Wu2^T+bu2)); out = u2 + hs2.
// BN folded into weight frags + bias; ht read coalesced from tiled layout.
// ---------------------------------------------------------------------------
__global__ __launch_bounds__(256, 2) void k3_update(
    const float* __restrict__ x, const bf16* __restrict__ ht,
    const float* __restrict__ Wskip, const float* __restrict__ bskip,
    const float* __restrict__ Wu1, const float* __restrict__ bu1,
    const float* __restrict__ g1, const float* __restrict__ be1,
    const float* __restrict__ rm1, const float* __restrict__ rv1,
    const float* __restrict__ Wu2, const float* __restrict__ bu2,
    const float* __restrict__ g2, const float* __restrict__ be2,
    const float* __restrict__ rm2, const float* __restrict__ rv2,
    float* __restrict__ out)
{
  __shared__ short hs2L[4][32][LS];
  __shared__ short u1L[4][32][LS];
  const int tid = threadIdx.x;
  const int wv = tid >> 6, lane = tid & 63, r = lane & 15, g = lane >> 4;
  const int wid = blockIdx.x * 4 + wv;

  // ---- weights with BN folded: W1' = sc1 o Wu1, b1' = be1 + (bu1-rm1)*sc1 ----
  short8 wsk[4][2], w1f[4][2], w2f[4][2];
  float bskv[4];
  f32x4 b1c[4], b2c[4];
  #pragma unroll
  for (int cb = 0; cb < 4; ++cb) {
    const int row = cb*16 + r;
    const float s1 = g1[row] * rsqrtf(rv1[row] + 1e-5f);
    const float s2 = g2[row] * rsqrtf(rv2[row] + 1e-5f);
    #pragma unroll
    for (int s = 0; s < 2; ++s) {
      const int o = row*64 + s*32 + g*8;
      wsk[cb][s] = ldfrag(Wskip + o);
      w1f[cb][s] = ldfrag_s(Wu1 + o, s1);
      w2f[cb][s] = ldfrag_s(Wu2 + o, s2);
    }
    bskv[cb] = bskip[row];
    const int o4 = cb*16 + 4*g;
    f32x4 gg1 = *(const f32x4*)(g1 + o4),  vv1 = *(const f32x4*)(rv1 + o4);
    f32x4 mm1 = *(const f32x4*)(rm1 + o4), bb1 = *(const f32x4*)(be1 + o4);
    f32x4 u1b = *(const f32x4*)(bu1 + o4);
    f32x4 gg2 = *(const f32x4*)(g2 + o4),  vv2 = *(const f32x4*)(rv2 + o4);
    f32x4 mm2 = *(const f32x4*)(rm2 + o4), bb2 = *(const f32x4*)(be2 + o4);
    f32x4 u2b = *(const f32x4*)(bu2 + o4);
    #pragma unroll
    for (int q = 0; q < 4; ++q) {
      const float c1 = gg1[q] * rsqrtf(vv1[q] + 1e-5f);
      b1c[cb][q] = bb1[q] + (u1b[q] - mm1[q]) * c1;
      const float c2 = gg2[q] * rsqrtf(vv2[q] + 1e-5f);
      b2c[cb][q] = bb2[q] + (u2b[q] - mm2[q]) * c2;
    }
  }

  size_t pb = (size_t)wid * 128;

  float4 xr[8];
  #pragma unroll
  for (int h = 0; h < 2; ++h) {
    const float* xp = x + (pb + h*16 + r)*64 + g*8;
    xr[4*h+0] = *(const float4*)(xp);
    xr[4*h+1] = *(const float4*)(xp + 4);
    xr[4*h+2] = *(const float4*)(xp + 32);
    xr[4*h+3] = *(const float4*)(xp + 36);
  }

  for (int t = 0; t < 4; ++t, pb += 32) {
    short8 xf[2][2];
    xf[0][0] = cvt8(xr[0], xr[1]);  xf[0][1] = cvt8(xr[2], xr[3]);
    xf[1][0] = cvt8(xr[4], xr[5]);  xf[1][1] = cvt8(xr[6], xr[7]);
    if (t < 3) {
      #pragma unroll
      for (int h = 0; h < 2; ++h) {
        const float* xp = x + (pb + 32 + h*16 + r)*64 + g*8;
        xr[4*h+0] = *(const float4*)(xp);
        xr[4*h+1] = *(const float4*)(xp + 4);
        xr[4*h+2] = *(const float4*)(xp + 32);
        xr[4*h+3] = *(const float4*)(xp + 36);
      }
    }
    // h tile loads: tiled layout, 1KB-contiguous short8 per inst
    const size_t tbase = (pb >> 5) * 2048;
    short8 hv8[4];
    #pragma unroll
    for (int cb = 0; cb < 4; ++cb)
      hv8[cb] = *(const short8*)(ht + tbase + (cb*16 + r)*32 + g*8);

    // skip GEMM (normal): C[row=pos(th*16+4g+q)][col=ch(cb*16+r)]
    f32x4 acc[4][2];
    #pragma unroll
    for (int cb = 0; cb < 4; ++cb) {
      acc[cb][0] = (f32x4){bskv[cb], bskv[cb], bskv[cb], bskv[cb]};
      acc[cb][1] = acc[cb][0];
    }
    #pragma unroll
    for (int cb = 0; cb < 4; ++cb)
      #pragma unroll
      for (int s = 0; s < 2; ++s) {
        acc[cb][0] = MFMA(xf[0][s], wsk[cb][s], acc[cb][0]);
        acc[cb][1] = MFMA(xf[1][s], wsk[cb][s], acc[cb][1]);
      }
    #pragma unroll
    for (int cb = 0; cb < 4; ++cb)
      #pragma unroll
      for (int th = 0; th < 2; ++th)
        #pragma unroll
        for (int q = 0; q < 4; ++q) acc[cb][th][q] += s2f(hv8[cb][th*4+q]);
    // hs2 -> LDS [pos][ch] (scalar transpose-writes)
    #pragma unroll
    for (int cb = 0; cb < 4; ++cb)
      #pragma unroll
      for (int th = 0; th < 2; ++th)
        #pragma unroll
        for (int q = 0; q < 4; ++q)
          hs2L[wv][th*16 + 4*g + q][cb*16 + r] = f2bs(acc[cb][th][q]);
    short8 hf[2][2];
    #pragma unroll
    for (int th = 0; th < 2; ++th)
      #pragma unroll
      for (int s = 0; s < 2; ++s)
        hf[th][s] = *(const short8*)&hs2L[wv][th*16 + r][s*32 + g*8];

    // u1 (transposed, BN folded): C[row=ch(4g+q)][col=pos(r)]
    f32x4 a1[4][2];
    #pragma unroll
    for (int cb = 0; cb < 4; ++cb) { a1[cb][0] = b1c[cb]; a1[cb][1] = b1c[cb]; }
    #pragma unroll
    for (int cb = 0; cb < 4; ++cb)
      #pragma unroll
      for (int s = 0; s < 2; ++s) {
        a1[cb][0] = MFMA(w1f[cb][s], hf[0][s], a1[cb][0]);
        a1[cb][1] = MFMA(w1f[cb][s], hf[1][s], a1[cb][1]);
      }
    #pragma unroll
    for (int cb = 0; cb < 4; ++cb)
      #pragma unroll
      for (int th = 0; th < 2; ++th) {
        short4v v;
        #pragma unroll
        for (int q = 0; q < 4; ++q) v[q] = f2bs(fmaxf(a1[cb][th][q], 0.f));
        *(short4v*)&u1L[wv][th*16 + r][cb*16 + 4*g] = v;
      }
    short8 uf[2][2];
    #pragma unroll
    for (int th = 0; th < 2; ++th)
      #pragma unroll
      for (int s = 0; s < 2; ++s)
        uf[th][s] = *(const short8*)&u1L[wv][th*16 + r][s*32 + g*8];

    // u2 (transposed, BN folded) + residual -> out
    f32x4 a2[4][2];
    #pragma unroll
    for (int cb = 0; cb < 4; ++cb) { a2[cb][0] = b2c[cb]; a2[cb][1] = b2c[cb]; }
    #pragma unroll
    for (int cb = 0; cb < 4; ++cb)
      #pragma unroll
      for (int s = 0; s < 2; ++s) {
        a2[cb][0] = MFMA(w2f[cb][s], uf[0][s], a2[cb][0]);
        a2[cb][1] = MFMA(w2f[cb][s], uf[1][s], a2[cb][1]);
      }
    #pragma unroll
    for (int cb = 0; cb < 4; ++cb)
      #pragma unroll
      for (int th = 0; th < 2; ++th) {
        short4v hres = *(const short4v*)&hs2L[wv][th*16 + r][cb*16 + 4*g];
        f32x4 res;
        #pragma unroll
        for (int q = 0; q < 4; ++q)
          res[q] = fmaxf(a2[cb][th][q], 0.f) + s2f(hres[q]);
        *(f32x4*)(out + (pb + th*16 + r)*64 + cb*16 + 4*g) = res;
      }
  }
}

// ---------------------------------------------------------------------------
extern "C" void kernel_launch(void* const* d_in, const int* in_sizes, int n_in,
                              void* d_out, int out_size, void* d_ws, size_t ws_size,
                              hipStream_t stream) {
  const float* x     = (const float*)d_in[0];
  const float* w_m1  = (const float*)d_in[1];
  const float* b_m1  = (const float*)d_in[2];
  const float* w_m2  = (const float*)d_in[3];
  const float* b_m2  = (const float*)d_in[4];
  const float* Wskip = (const float*)d_in[5];
  const float* bskip = (const float*)d_in[6];
  const float* Wu1   = (const float*)d_in[7];
  const float* bu1   = (const float*)d_in[8];
  const float* g1    = (const float*)d_in[9];
  const float* be1   = (const float*)d_in[10];
  const float* rm1   = (const float*)d_in[11];
  const float* rv1   = (const float*)d_in[12];
  const float* Wu2   = (const float*)d_in[13];
  const float* bu2   = (const float*)d_in[14];
  const float* g2    = (const float*)d_in[15];
  const float* be2   = (const float*)d_in[16];
  const float* rm2   = (const float*)d_in[17];
  const float* rv2   = (const float*)d_in[18];
  float* out = (float*)d_out;

  bf16* m1t = (bf16*)d_ws;
  bf16* m2t = m1t + (size_t)64 * NT;
  bf16* ht  = m1t;   // safe alias: each k2 block overwrites only its own region

  k1_mlp<<<1088, 256, 0, stream>>>(x, w_m1, b_m1, w_m2, b_m2, m1t, m2t);

  // regions (positions): (128,32)@0  (64,48)@131072  (32,64)@278528  (16,96)@409600
  k2_spatial<32><<<128*64, 256, 0, stream>>>(m1t, m2t, ht, 0);
  k2_spatial<48><<< 64*64, 256, 0, stream>>>(m1t, m2t, ht, 131072);
  k2_spatial<64><<< 32*64, 256, 0, stream>>>(m1t, m2t, ht, 278528);
  k2_spatial<96><<< 16*64, 256, 0, stream>>>(m1t, m2t, ht, 409600);

  k3_update<<<1088, 256, 0, stream>>>(x, ht, Wskip, bskip,
                                      Wu1, bu1, g1, be1, rm1, rv1,
                                      Wu2, bu2, g2, be2, rm2, rv2, out);
}

// Round 7
// 544.578 us; speedup vs baseline: 1.0442x; 1.0442x over previous
//
#include <hip/hip_runtime.h>
#include <hip/hip_bf16.h>

#define NT 557056
typedef __hip_bfloat16 bf16;
typedef __attribute__((ext_vector_type(8))) short short8;
typedef __attribute__((ext_vector_type(4))) short short4v;
typedef __attribute__((ext_vector_type(4))) float f32x4;

// Tiled intermediate layout: [tile of 32 positions][64 ch][32 shorts],
// within-tile slot s = g*8 + th*4 + q  <->  tile-local pos p = th*16 + 4*g + q.
// Key property: slots 8a..8a+3 = pos 4a..4a+3; slots 8a+4..8a+7 = pos 16+4a..+3
// (two contiguous 4-pos runs per 8-slot group -> vector de-permute).

__device__ __forceinline__ short f2bs(float f){ bf16 h = __float2bfloat16(f); return *(short*)&h; }
__device__ __forceinline__ float s2f(short s){ bf16 h = *(bf16*)&s; return __bfloat162float(h); }

__device__ __forceinline__ short8 cvt8(float4 a, float4 b){
  short8 r;
  r[0]=f2bs(a.x); r[1]=f2bs(a.y); r[2]=f2bs(a.z); r[3]=f2bs(a.w);
  r[4]=f2bs(b.x); r[5]=f2bs(b.y); r[6]=f2bs(b.z); r[7]=f2bs(b.w);
  return r;
}
// 8 consecutive f32 -> bf16x8 MFMA fragment.
// A-role: lane holds A[row=l&15][k=(l>>4)*8+j]; B-role: B[k=(l>>4)*8+j][col=l&15].
__device__ __forceinline__ short8 ldfrag(const float* __restrict__ p){
  return cvt8(*(const float4*)p, *(const float4*)(p + 4));
}
__device__ __forceinline__ short8 ldfrag_s(const float* __restrict__ p, float s){
  float4 a = *(const float4*)p, b = *(const float4*)(p + 4);
  a.x*=s; a.y*=s; a.z*=s; a.w*=s; b.x*=s; b.y*=s; b.z*=s; b.w*=s;
  return cvt8(a, b);
}
#define MFMA(a,b,c) __builtin_amdgcn_mfma_f32_16x16x32_bf16(a, b, c, 0, 0, 0)

#define LS 72   // LDS row stride in shorts (144B rows, 16B-aligned)

// ---------------------------------------------------------------------------
// K1: m1 = MLP(x; w_m1), m2 = MLP(x; w_m2). 4352 waves x 4 tiles x 32 pos.
// (unchanged from round 6)
// ---------------------------------------------------------------------------
__global__ __launch_bounds__(256, 2) void k1_mlp(
    const float* __restrict__ x,
    const float* __restrict__ w_m1, const float* __restrict__ b_m1,
    const float* __restrict__ w_m2, const float* __restrict__ b_m2,
    bf16* __restrict__ m1t, bf16* __restrict__ m2t)
{
  __shared__ short yL[4][32][LS];
  const int tid = threadIdx.x;
  const int wv = tid >> 6, lane = tid & 63, r = lane & 15, g = lane >> 4;
  const int wid = blockIdx.x * 4 + wv;

  short8 wf[4][4][2];
  #pragma unroll
  for (int cb = 0; cb < 4; ++cb)
    #pragma unroll
    for (int s = 0; s < 2; ++s) {
      const int o = (cb*16 + r)*64 + s*32 + g*8;
      wf[0][cb][s] = ldfrag(w_m1 + o);
      wf[1][cb][s] = ldfrag(w_m1 + 4096 + o);
      wf[2][cb][s] = ldfrag(w_m2 + o);
      wf[3][cb][s] = ldfrag(w_m2 + 4096 + o);
    }
  f32x4 b0v[2][4];
  float b1v[2][4];
  #pragma unroll
  for (int m = 0; m < 2; ++m) {
    const float* bb = m ? b_m2 : b_m1;
    #pragma unroll
    for (int cb = 0; cb < 4; ++cb) {
      b0v[m][cb] = *(const f32x4*)(bb + cb*16 + 4*g);
      b1v[m][cb] = bb[64 + cb*16 + r];
    }
  }

  size_t pb = (size_t)wid * 128;

  float4 xr[8];
  #pragma unroll
  for (int h = 0; h < 2; ++h) {
    const float* xp = x + (pb + h*16 + r)*64 + g*8;
    xr[4*h+0] = *(const float4*)(xp);
    xr[4*h+1] = *(const float4*)(xp + 4);
    xr[4*h+2] = *(const float4*)(xp + 32);
    xr[4*h+3] = *(const float4*)(xp + 36);
  }

  for (int t = 0; t < 4; ++t, pb += 32) {
    short8 xf[2][2];
    xf[0][0] = cvt8(xr[0], xr[1]);  xf[0][1] = cvt8(xr[2], xr[3]);
    xf[1][0] = cvt8(xr[4], xr[5]);  xf[1][1] = cvt8(xr[6], xr[7]);
    if (t < 3) {
      #pragma unroll
      for (int h = 0; h < 2; ++h) {
        const float* xp = x + (pb + 32 + h*16 + r)*64 + g*8;
        xr[4*h+0] = *(const float4*)(xp);
        xr[4*h+1] = *(const float4*)(xp + 4);
        xr[4*h+2] = *(const float4*)(xp + 32);
        xr[4*h+3] = *(const float4*)(xp + 36);
      }
    }
    const size_t tbase = (pb >> 5) * 2048;
    #pragma unroll
    for (int m = 0; m < 2; ++m) {
      f32x4 acc[4][2];
      #pragma unroll
      for (int cb = 0; cb < 4; ++cb) { acc[cb][0] = b0v[m][cb]; acc[cb][1] = b0v[m][cb]; }
      #pragma unroll
      for (int cb = 0; cb < 4; ++cb)
        #pragma unroll
        for (int s = 0; s < 2; ++s) {
          acc[cb][0] = MFMA(wf[2*m][cb][s], xf[0][s], acc[cb][0]);
          acc[cb][1] = MFMA(wf[2*m][cb][s], xf[1][s], acc[cb][1]);
        }
      #pragma unroll
      for (int cb = 0; cb < 4; ++cb)
        #pragma unroll
        for (int th = 0; th < 2; ++th) {
          short4v v;
          #pragma unroll
          for (int q = 0; q < 4; ++q) v[q] = f2bs(fmaxf(acc[cb][th][q], 0.f));
          *(short4v*)&yL[wv][th*16 + r][cb*16 + 4*g] = v;
        }
      short8 af[2][2];
      #pragma unroll
      for (int th = 0; th < 2; ++th)
        #pragma unroll
        for (int s = 0; s < 2; ++s)
          af[th][s] = *(const short8*)&yL[wv][th*16 + r][s*32 + g*8];
      f32x4 acc2[4][2];
      #pragma unroll
      for (int cb = 0; cb < 4; ++cb) {
        const float bv = b1v[m][cb];
        acc2[cb][0] = (f32x4){bv,bv,bv,bv};
        acc2[cb][1] = (f32x4){bv,bv,bv,bv};
      }
      #pragma unroll
      for (int cb = 0; cb < 4; ++cb)
        #pragma unroll
        for (int s = 0; s < 2; ++s) {
          acc2[cb][0] = MFMA(af[0][s], wf[2*m+1][cb][s], acc2[cb][0]);
          acc2[cb][1] = MFMA(af[1][s], wf[2*m+1][cb][s], acc2[cb][1]);
        }
      bf16* op = m ? m2t : m1t;
      #pragma unroll
      for (int cb = 0; cb < 4; ++cb) {
        short8 v;
        #pragma unroll
        for (int th = 0; th < 2; ++th)
          #pragma unroll
          for (int q = 0; q < 4; ++q) v[th*4+q] = f2bs(fmaxf(acc2[cb][th][q], 0.f));
        *(short8*)(op + tbase + (cb*16 + r)*32 + g*8) = v;
      }
    }
  }
}

// ---------------------------------------------------------------------------
// K2 (NEW): per (block, ch-group) spatial matmul H = M1 @ M2 via MFMA.
// Stage M1 de-permuted [ch][i][j] (vector b64), M2 transposed [ch][k][j]
// (scalar), K zero-padded to 64 for n=48; compute 16x16 C-tiles with
// mfma_f32_16x16x32_bf16; C staged bf16 in LDS; cooperative permuted-short8
// epilogue stores the tiled layout. ht aliases m1t: all global reads complete
// before barrier #1, stores happen after barrier #2 -> safe.
// ---------------------------------------------------------------------------
template<int N, int CH, int NP, int CP>
__global__ __launch_bounds__(256) void k2_mfma(
    const bf16* __restrict__ m1t, const bf16* __restrict__ m2t,
    bf16* __restrict__ ht, int off)
{
  constexpr int TPB = N*N/32;     // 32-pos tiles per plane
  constexpr int NT16 = N/16;
  constexpr int TPC = NT16*NT16;  // 16x16 C-tiles per channel
  constexpr int KS = (N + 31)/32; // K-steps of 32 (2 for n=48 with zero pad)
  constexpr int GRP = 64/CH;

  __shared__ short Am[CH][N][NP];   // M1: [ch][i][j]
  __shared__ short Bt[CH][N][NP];   // M2^T: [ch][k][j]
  __shared__ short Cs[CH][N][CP];   // H (bf16): [ch][i][k]

  const int tid = threadIdx.x;
  const int grp = blockIdx.x % GRP;
  const int b   = blockIdx.x / GRP;
  const int c0  = grp * CH;
  const size_t base_tile = ((size_t)off + (size_t)b * N * N) >> 5;

  // ---- stage M1 (de-permuted) and M2^T ----
  constexpr int UPT = CH * TPB * 4;   // short8 units per tensor
  for (int u = tid; u < 2*UPT; u += 256) {
    int uu = u;
    const bf16* src = m1t;
    bool isA = true;
    if (uu >= UPT) { uu -= UPT; src = m2t; isA = false; }
    const int a   = uu & 3;
    const int cc  = (uu >> 2) % CH;
    const int tau = (uu >> 2) / CH;
    short8 v = *(const short8*)(src + (base_tile + tau)*2048 + (size_t)(c0+cc)*32 + a*8);
    const int p0 = tau*32 + 4*a;
    #pragma unroll
    for (int h = 0; h < 2; ++h) {
      const int p = p0 + h*16;
      const int row = p / N, col = p % N;   // (i,j) for M1 ; (j,k) for M2
      if (isA) {
        short4v w; w[0]=v[h*4+0]; w[1]=v[h*4+1]; w[2]=v[h*4+2]; w[3]=v[h*4+3];
        *(short4v*)&Am[cc][row][col] = w;
      } else {
        #pragma unroll
        for (int q = 0; q < 4; ++q) Bt[cc][col+q][row] = v[h*4+q];
      }
    }
  }
  // ---- zero-fill K pad (n=48: j in [48,64)) ----
  if constexpr (N == 48) {
    for (int u = tid; u < CH*N*4*2; u += 256) {
      int uu = u; bool isA = uu < CH*N*4; if (!isA) uu -= CH*N*4;
      const int seg = uu & 3, row = (uu>>2) % N, cc = (uu>>2) / N;
      short4v z = {0,0,0,0};
      if (isA) *(short4v*)&Am[cc][row][48 + seg*4] = z;
      else     *(short4v*)&Bt[cc][row][48 + seg*4] = z;
    }
  }
  __syncthreads();

  // ---- MFMA compute: one 16x16 C-tile per wave-iteration ----
  const int wv = tid >> 6, lane = tid & 63, r = lane & 15, g = lane >> 4;
  for (int idx = wv; idx < CH*TPC; idx += 4) {
    const int cc = idx / TPC, t = idx % TPC;
    const int i0 = (t / NT16) * 16, k0 = (t % NT16) * 16;
    f32x4 acc = {0.f, 0.f, 0.f, 0.f};
    #pragma unroll
    for (int ks = 0; ks < KS; ++ks) {
      short8 afr = *(const short8*)&Am[cc][i0 + r][ks*32 + g*8];
      short8 bfr = *(const short8*)&Bt[cc][k0 + r][ks*32 + g*8];
      acc = MFMA(afr, bfr, acc);
    }
    #pragma unroll
    for (int q = 0; q < 4; ++q) Cs[cc][i0 + 4*g + q][k0 + r] = f2bs(acc[q]);
  }
  __syncthreads();

  // ---- epilogue: permuted coalesced short8 stores (tiled layout) ----
  for (int u = tid; u < UPT; u += 256) {
    const int a   = u & 3;
    const int cc  = (u >> 2) % CH;
    const int tau = (u >> 2) / CH;
    const int p0  = tau*32 + 4*a;
    short8 v;
    #pragma unroll
    for (int h = 0; h < 2; ++h) {
      const int p = p0 + h*16;
      const int i = p / N, k = p % N;
      short4v w = *(const short4v*)&Cs[cc][i][k];
      v[h*4+0]=w[0]; v[h*4+1]=w[1]; v[h*4+2]=w[2]; v[h*4+3]=w[3];
    }
    *(short8*)(ht + (base_tile + tau)*2048 + (size_t)(c0+cc)*32 + a*8) = v;
  }
}

// ---------------------------------------------------------------------------
// K3: (unchanged from round 6)
// ---------------------------------------------------------------------------
__global__ __launch_bounds__(256, 2) void k3_update(
    const float* __restrict__ x, const bf16* __restrict__ ht,
    const float* __restrict__ Wskip, const float* __restrict__ bskip,
    const float* __restrict__ Wu1, const float* __restrict__ bu1,
    const float* __restrict__ g1, const float* __restrict__ be1,
    const float* __restrict__ rm1, const float* __restrict__ rv1,
    const float* __restrict__ Wu2, const float* __restrict__ bu2,
    const float* __restrict__ g2, const float* __restrict__ be2,
    const float* __restrict__ rm2, const float* __restrict__ rv2,
    float* __restrict__ out)
{
  __shared__ short hs2L[4][32][LS];
  __shared__ short u1L[4][32][LS];
  const int tid = threadIdx.x;
  const int wv = tid >> 6, lane = tid & 63, r = lane & 15, g = lane >> 4;
  const int wid = blockIdx.x * 4 + wv;

  short8 wsk[4][2], w1f[4][2], w2f[4][2];
  float bskv[4];
  f32x4 b1c[4], b2c[4];
  #pragma unroll
  for (int cb = 0; cb < 4; ++cb) {
    const int row = cb*16 + r;
    const float s1 = g1[row] * rsqrtf(rv1[row] + 1e-5f);
    const float s2 = g2[row] * rsqrtf(rv2[row] + 1e-5f);
    #pragma unroll
    for (int s = 0; s < 2; ++s) {
      const int o = row*64 + s*32 + g*8;
      wsk[cb][s] = ldfrag(Wskip + o);
      w1f[cb][s] = ldfrag_s(Wu1 + o, s1);
      w2f[cb][s] = ldfrag_s(Wu2 + o, s2);
    }
    bskv[cb] = bskip[row];
    const int o4 = cb*16 + 4*g;
    f32x4 gg1 = *(const f32x4*)(g1 + o4),  vv1 = *(const f32x4*)(rv1 + o4);
    f32x4 mm1 = *(const f32x4*)(rm1 + o4), bb1 = *(const f32x4*)(be1 + o4);
    f32x4 u1b = *(const f32x4*)(bu1 + o4);
    f32x4 gg2 = *(const f32x4*)(g2 + o4),  vv2 = *(const f32x4*)(rv2 + o4);
    f32x4 mm2 = *(const f32x4*)(rm2 + o4), bb2 = *(const f32x4*)(be2 + o4);
    f32x4 u2b = *(const f32x4*)(bu2 + o4);
    #pragma unroll
    for (int q = 0; q < 4; ++q) {
      const float c1 = gg1[q] * rsqrtf(vv1[q] + 1e-5f);
      b1c[cb][q] = bb1[q] + (u1b[q] - mm1[q]) * c1;
      const float c2 = gg2[q] * rsqrtf(vv2[q] + 1e-5f);
      b2c[cb][q] = bb2[q] + (u2b[q] - mm2[q]) * c2;
    }
  }

  size_t pb = (size_t)wid * 128;

  float4 xr[8];
  #pragma unroll
  for (int h = 0; h < 2; ++h) {
    const float* xp = x + (pb + h*16 + r)*64 + g*8;
    xr[4*h+0] = *(const float4*)(xp);
    xr[4*h+1] = *(const float4*)(xp + 4);
    xr[4*h+2] = *(const float4*)(xp + 32);
    xr[4*h+3] = *(const float4*)(xp + 36);
  }

  for (int t = 0; t < 4; ++t, pb += 32) {
    short8 xf[2][2];
    xf[0][0] = cvt8(xr[0], xr[1]);  xf[0][1] = cvt8(xr[2], xr[3]);
    xf[1][0] = cvt8(xr[4], xr[5]);  xf[1][1] = cvt8(xr[6], xr[7]);
    if (t < 3) {
      #pragma unroll
      for (int h = 0; h < 2; ++h) {
        const float* xp = x + (pb + 32 + h*16 + r)*64 + g*8;
        xr[4*h+0] = *(const float4*)(xp);
        xr[4*h+1] = *(const float4*)(xp + 4);
        xr[4*h+2] = *(const float4*)(xp + 32);
        xr[4*h+3] = *(const float4*)(xp + 36);
      }
    }
    const size_t tbase = (pb >> 5) * 2048;
    short8 hv8[4];
    #pragma unroll
    for (int cb = 0; cb < 4; ++cb)
      hv8[cb] = *(const short8*)(ht + tbase + (cb*16 + r)*32 + g*8);

    f32x4 acc[4][2];
    #pragma unroll
    for (int cb = 0; cb < 4; ++cb) {
      acc[cb][0] = (f32x4){bskv[cb], bskv[cb], bskv[cb], bskv[cb]};
      acc[cb][1] = acc[cb][0];
    }
    #pragma unroll
    for (int cb = 0; cb < 4; ++cb)
      #pragma unroll
      for (int s = 0; s < 2; ++s) {
        acc[cb][0] = MFMA(xf[0][s], wsk[cb][s], acc[cb][0]);
        acc[cb][1] = MFMA(xf[1][s], wsk[cb][s], acc[cb][1]);
      }
    #pragma unroll
    for (int cb = 0; cb < 4; ++cb)
      #pragma unroll
      for (int th = 0; th < 2; ++th)
        #pragma unroll
        for (int q = 0; q < 4; ++q) acc[cb][th][q] += s2f(hv8[cb][th*4+q]);
    #pragma unroll
    for (int cb = 0; cb < 4; ++cb)
      #pragma unroll
      for (int th = 0; th < 2; ++th)
        #pragma unroll
        for (int q = 0; q < 4; ++q)
          hs2L[wv][th*16 + 4*g + q][cb*16 + r] = f2bs(acc[cb][th][q]);
    short8 hf[2][2];
    #pragma unroll
    for (int th = 0; th < 2; ++th)
      #pragma unroll
      for (int s = 0; s < 2; ++s)
        hf[th][s] = *(const short8*)&hs2L[wv][th*16 + r][s*32 + g*8];

    f32x4 a1[4][2];
    #pragma unroll
    for (int cb = 0; cb < 4; ++cb) { a1[cb][0] = b1c[cb]; a1[cb][1] = b1c[cb]; }
    #pragma unroll
    for (int cb = 0; cb < 4; ++cb)
      #pragma unroll
      for (int s = 0; s < 2; ++s) {
        a1[cb][0] = MFMA(w1f[cb][s], hf[0][s], a1[cb][0]);
        a1[cb][1] = MFMA(w1f[cb][s], hf[1][s], a1[cb][1]);
      }
    #pragma unroll
    for (int cb = 0; cb < 4; ++cb)
      #pragma unroll
      for (int th = 0; th < 2; ++th) {
        short4v v;
        #pragma unroll
        for (int q = 0; q < 4; ++q) v[q] = f2bs(fmaxf(a1[cb][th][q], 0.f));
        *(short4v*)&u1L[wv][th*16 + r][cb*16 + 4*g] = v;
      }
    short8 uf[2][2];
    #pragma unroll
    for (int th = 0; th < 2; ++th)
      #pragma unroll
      for (int s = 0; s < 2; ++s)
        uf[th][s] = *(const short8*)&u1L[wv][th*16 + r][s*32 + g*8];

    f32x4 a2[4][2];
    #pragma unroll
    for (int cb = 0; cb < 4; ++cb) { a2[cb][0] = b2c[cb]; a2[cb][1] = b2c[cb]; }
    #pragma unroll
    for (int cb = 0; cb < 4; ++cb)
      #pragma unroll
      for (int s = 0; s < 2; ++s) {
        a2[cb][0] = MFMA(w2f[cb][s], uf[0][s], a2[cb][0]);
        a2[cb][1] = MFMA(w2f[cb][s], uf[1][s], a2[cb][1]);
      }
    #pragma unroll
    for (int cb = 0; cb < 4; ++cb)
      #pragma unroll
      for (int th = 0; th < 2; ++th) {
        short4v hres = *(const short4v*)&hs2L[wv][th*16 + r][cb*16 + 4*g];
        f32x4 res;
        #pragma unroll
        for (int q = 0; q < 4; ++q)
          res[q] = fmaxf(a2[cb][th][q], 0.f) + s2f(hres[q]);
        *(f32x4*)(out + (pb + th*16 + r)*64 + cb*16 + 4*g) = res;
      }
  }
}

// ---------------------------------------------------------------------------
extern "C" void kernel_launch(void* const* d_in, const int* in_sizes, int n_in,
                              void* d_out, int out_size, void* d_ws, size_t ws_size,
                              hipStream_t stream) {
  const float* x     = (const float*)d_in[0];
  const float* w_m1  = (const float*)d_in[1];
  const float* b_m1  = (const float*)d_in[2];
  const float* w_m2  = (const float*)d_in[3];
  const float* b_m2  = (const float*)d_in[4];
  const float* Wskip = (const float*)d_in[5];
  const float* bskip = (const float*)d_in[6];
  const float* Wu1   = (const float*)d_in[7];
  const float* bu1   = (const float*)d_in[8];
  const float* g1    = (const float*)d_in[9];
  const float* be1   = (const float*)d_in[10];
  const float* rm1   = (const float*)d_in[11];
  const float* rv1   = (const float*)d_in[12];
  const float* Wu2   = (const float*)d_in[13];
  const float* bu2   = (const float*)d_in[14];
  const float* g2    = (const float*)d_in[15];
  const float* be2   = (const float*)d_in[16];
  const float* rm2   = (const float*)d_in[17];
  const float* rv2   = (const float*)d_in[18];
  float* out = (float*)d_out;

  bf16* m1t = (bf16*)d_ws;
  bf16* m2t = m1t + (size_t)64 * NT;
  bf16* ht  = m1t;   // safe alias: k2 wg reads its chunks before writing them

  k1_mlp<<<1088, 256, 0, stream>>>(x, w_m1, b_m1, w_m2, b_m2, m1t, m2t);

  // regions (positions): (128,32)@0  (64,48)@131072  (32,64)@278528  (16,96)@409600
  k2_mfma<32, 8, 40,  40><<<128 *  8, 256, 0, stream>>>(m1t, m2t, ht, 0);
  k2_mfma<48, 4, 72,  56><<< 64 * 16, 256, 0, stream>>>(m1t, m2t, ht, 131072);
  k2_mfma<64, 2, 72,  72><<< 32 * 32, 256, 0, stream>>>(m1t, m2t, ht, 278528);
  k2_mfma<96, 1, 104, 104><<< 16 * 64, 256, 0, stream>>>(m1t, m2t, ht, 409600);

  k3_update<<<1088, 256, 0, stream>>>(x, ht, Wskip, bskip,
                                      Wu1, bu1, g1, be1, rm1, rv1,
                                      Wu2, bu2, g2, be2, rm2, rv2, out);
}